// Round 1
// baseline (205.983 us; speedup 1.0000x reference)
//
#include <hip/hip_runtime.h>
#include <hip/hip_bf16.h>

#define N_NODES 10000
#define NFEAT   512
#define NHID    256
#define NHID2   128
#define CAP     128   // max nnz per adj row we store (binomial(10000,0.005): mean 50, sd 7 -> 128 is >11 sigma)

typedef __attribute__((ext_vector_type(8))) short bf16x8;
typedef __attribute__((ext_vector_type(4))) float f32x4;

__device__ __forceinline__ ushort f2bf(float f){
  union { float f; unsigned u; } v; v.f = f;
  unsigned r = v.u + 0x7FFFu + ((v.u >> 16) & 1u);   // round-to-nearest-even
  return (ushort)(r >> 16);
}

// ---- f32 -> bf16, 4 elems/thread, exact-grid ----
__global__ void k_cvt_bf16(const float* __restrict__ in, ushort* __restrict__ out, int n){
  int i = (blockIdx.x * blockDim.x + threadIdx.x) * 4;
  if (i + 3 < n){
    float4 q = *(const float4*)(in + i);
    ushort4 o;
    o.x = f2bf(q.x); o.y = f2bf(q.y); o.z = f2bf(q.z); o.w = f2bf(q.w);
    *(ushort4*)(out + i) = o;
  } else {
    for (; i < n; i++) out[i] = f2bf(in[i]);
  }
}

// ---- W[K][N] f32 -> Wt[N][K] bf16 (tiny matrices, coalesced writes) ----
__global__ void k_cvt_bf16_t(const float* __restrict__ W, ushort* __restrict__ Wt, int K, int N){
  int id = blockIdx.x * blockDim.x + threadIdx.x;
  if (id >= K * N) return;
  int n = id / K, k = id - n * K;
  Wt[id] = f2bf(W[(size_t)k * N + n]);
}

// ---- bf16 MFMA GEMM: C[M][N] = A[M][K] @ Bt[N][K]^T ----
// 4 waves in 2x2; each wave computes (WR*16) x (WC*16). No LDS: operands are
// small and L2/L3-resident; fragments load as contiguous short8 (16B/lane).
template<int WR, int WC>
__launch_bounds__(256)
__global__ void k_gemm_bf16(const ushort* __restrict__ A, const ushort* __restrict__ Bt,
                            float* __restrict__ C, int M, int N, int K){
  const int lane = threadIdx.x & 63;
  const int w    = threadIdx.x >> 6;
  const int wr   = w >> 1, wc = w & 1;
  const int r16  = lane & 15;
  const int kg   = lane >> 4;           // 0..3
  const int BM = 2 * WR * 16, BN = 2 * WC * 16;
  const int row0 = blockIdx.x * BM + wr * WR * 16;
  const int col0 = blockIdx.y * BN + wc * WC * 16;

  f32x4 acc[WR][WC];
  #pragma unroll
  for (int r = 0; r < WR; r++)
    #pragma unroll
    for (int c = 0; c < WC; c++)
      acc[r][c] = (f32x4){0.f, 0.f, 0.f, 0.f};

  for (int k0 = 0; k0 < K; k0 += 32){
    bf16x8 a[WR], b[WC];
    #pragma unroll
    for (int r = 0; r < WR; r++){
      int ar = row0 + r * 16 + r16;
      if (ar >= M) ar = M - 1;                       // clamp: safe read, store masked later
      a[r] = *(const bf16x8*)(A + (size_t)ar * K + k0 + kg * 8);
    }
    #pragma unroll
    for (int c = 0; c < WC; c++){
      int bc = col0 + c * 16 + r16;                  // grid sized so always < N
      b[c] = *(const bf16x8*)(Bt + (size_t)bc * K + k0 + kg * 8);
    }
    #pragma unroll
    for (int r = 0; r < WR; r++)
      #pragma unroll
      for (int c = 0; c < WC; c++)
        acc[r][c] = __builtin_amdgcn_mfma_f32_16x16x32_bf16(a[r], b[c], acc[r][c], 0, 0, 0);
  }

  // C/D layout (m89-verified): row = kg*4 + i, col = lane&15 within each 16x16 frag
  #pragma unroll
  for (int r = 0; r < WR; r++)
    #pragma unroll
    for (int c = 0; c < WC; c++){
      int col = col0 + c * 16 + r16;
      #pragma unroll
      for (int i = 0; i < 4; i++){
        int row = row0 + r * 16 + kg * 4 + i;
        if (row < M) C[(size_t)row * N + col] = acc[r][c][i];
      }
    }
}

// ---- SpMM layer 1: scan adj row, build sparse list (deterministic order),
//      H[i,:] = relu(sum_j a_ij * XW1[j,:] + b1), stored bf16. Also persist list. ----
__launch_bounds__(256)
__global__ void k_spmm1(const float* __restrict__ adj, const float* __restrict__ xw1,
                        const float* __restrict__ b1, ushort* __restrict__ Hb,
                        int* __restrict__ row_nnz, int* __restrict__ pj, float* __restrict__ pa){
  const int r = blockIdx.x;
  const int t = threadIdx.x;
  const float* row = adj + (size_t)r * N_NODES;

  __shared__ int   sc[256];
  __shared__ int   lj[CAP];
  __shared__ float la[CAP];

  // pass 1: count nonzeros in this thread's 40-element chunk (threads 0..249 active)
  const int start = t * 40;
  int cnt = 0;
  if (start < N_NODES){
    const float4* p = (const float4*)(row + start);
    #pragma unroll
    for (int v = 0; v < 10; v++){
      float4 q = p[v];
      cnt += (q.x != 0.f) + (q.y != 0.f) + (q.z != 0.f) + (q.w != 0.f);
    }
  }

  // inclusive Hillis-Steele prefix over 256 threads
  sc[t] = cnt; __syncthreads();
  for (int off = 1; off < 256; off <<= 1){
    int v_ = 0;
    if (t >= off) v_ = sc[t - off];
    __syncthreads();
    sc[t] += v_;
    __syncthreads();
  }
  int pos   = sc[t] - cnt;      // exclusive prefix -> deterministic, j-ascending order
  int total = sc[255];

  // pass 2 (row now L2-hot): compacted write to LDS + persist to workspace
  if (start < N_NODES && cnt > 0){
    const float4* p = (const float4*)(row + start);
    #pragma unroll
    for (int v = 0; v < 10; v++){
      float4 q = p[v];
      float qq[4] = {q.x, q.y, q.z, q.w};
      #pragma unroll
      for (int e = 0; e < 4; e++){
        if (qq[e] != 0.f){
          if (pos < CAP){
            lj[pos] = start + v * 4 + e;
            la[pos] = qq[e];
            pj[(size_t)r * CAP + pos] = start + v * 4 + e;
            pa[(size_t)r * CAP + pos] = qq[e];
          }
          pos++;
        }
      }
    }
  }
  __syncthreads();

  int n = min(total, CAP);
  if (t == 0) row_nnz[r] = n;

  // thread t owns output column t; gather rows of XW1 (coalesced 1KB reads)
  float acc = 0.f;
  for (int k = 0; k < n; k++)
    acc += la[k] * xw1[(size_t)lj[k] * NHID + t];
  float h = acc + b1[t];
  Hb[(size_t)r * NHID + t] = f2bf(fmaxf(h, 0.f));
}

// ---- SpMM layer 2: reuse stored sparse list, out = relu(sum a*HW2 + b2) ----
__launch_bounds__(128)
__global__ void k_spmm2(const int* __restrict__ row_nnz, const int* __restrict__ pj,
                        const float* __restrict__ pa, const float* __restrict__ hw2,
                        const float* __restrict__ b2, float* __restrict__ out){
  const int r = blockIdx.x;
  const int t = threadIdx.x;
  __shared__ int   lj[CAP];
  __shared__ float la[CAP];
  const int n = row_nnz[r];
  for (int k = t; k < n; k += 128){
    lj[k] = pj[(size_t)r * CAP + k];
    la[k] = pa[(size_t)r * CAP + k];
  }
  __syncthreads();
  float acc = 0.f;
  for (int k = 0; k < n; k++)
    acc += la[k] * hw2[(size_t)lj[k] * NHID2 + t];
  out[(size_t)r * NHID2 + t] = fmaxf(acc + b2[t], 0.f);
}

extern "C" void kernel_launch(void* const* d_in, const int* in_sizes, int n_in,
                              void* d_out, int out_size, void* d_ws, size_t ws_size,
                              hipStream_t stream){
  const float* x   = (const float*)d_in[0];
  const float* adj = (const float*)d_in[1];
  const float* W1  = (const float*)d_in[2];
  const float* b1  = (const float*)d_in[3];
  const float* W2  = (const float*)d_in[4];
  const float* b2  = (const float*)d_in[5];
  float* out = (float*)d_out;
  char*  ws  = (char*)d_ws;

  // workspace layout (all 16B-aligned), total ~41.3 MB
  ushort* xb  = (ushort*)(ws);              // x bf16:   10000*512*2 = 10,240,000
  ushort* w1t = (ushort*)(ws + 10240000);   // W1t bf16: 256*512*2   =    262,144
  ushort* w2t = (ushort*)(ws + 10502144);   // W2t bf16: 128*256*2   =     65,536
  float*  xw1 = (float*)(ws + 10567680);    // XW1 f32:  10000*256*4 = 10,240,000
  ushort* Hb  = (ushort*)(ws + 20807680);   // H bf16:   10000*256*2 =  5,120,000
  float*  hw2 = (float*)(ws + 25927680);    // HW2 f32:  10000*128*4 =  5,120,000
  int*    nnz = (int*)(ws + 31047680);      // 10000*4
  int*    pj  = (int*)(ws + 31087680);      // 10000*128*4 = 5,120,000
  float*  pa  = (float*)(ws + 36207680);    // 10000*128*4 = 5,120,000

  k_cvt_bf16  <<<5000, 256, 0, stream>>>(x, xb, N_NODES * NFEAT);
  k_cvt_bf16_t<<< 512, 256, 0, stream>>>(W1, w1t, NFEAT, NHID);
  k_cvt_bf16_t<<< 128, 256, 0, stream>>>(W2, w2t, NHID, NHID2);

  // GEMM1: XW1 = x @ W1   (M=10000, K=512, N=256), 128x128 block tile
  k_gemm_bf16<4,4><<<dim3(79, 2), 256, 0, stream>>>(xb, w1t, xw1, N_NODES, NHID, NFEAT);

  // layer-1 sparse aggregate + bias + relu (+ persist sparse adj)
  k_spmm1<<<N_NODES, 256, 0, stream>>>(adj, xw1, b1, Hb, nnz, pj, pa);

  // GEMM2: HW2 = H @ W2   (M=10000, K=256, N=128), 64x64 block tile
  k_gemm_bf16<2,2><<<dim3(157, 2), 256, 0, stream>>>(Hb, w2t, hw2, N_NODES, NHID2, NHID);

  // layer-2 sparse aggregate + bias + relu
  k_spmm2<<<N_NODES, 128, 0, stream>>>(nnz, pj, pa, hw2, b2, out);
}

// Round 2
// 161.746 us; speedup vs baseline: 1.2735x; 1.2735x over previous
//
#include <hip/hip_runtime.h>

#define N_NODES 10000
#define NFEAT   512
#define NHID    256
#define NHID2   128
#define CAP     128   // max nnz/row stored; binomial(10000,0.005) mean 50, sd 7 -> 128 is >11 sigma

typedef __attribute__((ext_vector_type(8))) short bf16x8;
typedef __attribute__((ext_vector_type(4))) float f32x4;

__device__ __forceinline__ ushort f2bf(float f){
  union { float f; unsigned u; } v; v.f = f;
  unsigned r = v.u + 0x7FFFu + ((v.u >> 16) & 1u);   // round-to-nearest-even
  return (ushort)(r >> 16);
}
__device__ __forceinline__ float bf2f(ushort u){
  union { unsigned u; float f; } v; v.u = ((unsigned)u) << 16; return v.f;
}

// ---- fused converts: x -> bf16, W1 -> W1t bf16, W2 -> W2t bf16 (one launch) ----
__global__ void k_cvt_all(const float* __restrict__ x, const float* __restrict__ W1,
                          const float* __restrict__ W2, ushort* __restrict__ xb,
                          ushort* __restrict__ w1t, ushort* __restrict__ w2t){
  const int b = blockIdx.x, t = threadIdx.x;
  if (b < 5000){                       // x: 5.12M elems, 4/thread, exact grid
    int i = (b * 256 + t) * 4;
    float4 q = *(const float4*)(x + i);
    ushort4 o; o.x = f2bf(q.x); o.y = f2bf(q.y); o.z = f2bf(q.z); o.w = f2bf(q.w);
    *(ushort4*)(xb + i) = o;
  } else if (b < 5512){                // W1t[n][k] = W1[k][n], 512x256 -> 256x512
    int id = (b - 5000) * 256 + t;     // 0..131071
    int n = id >> 9, k = id & 511;
    w1t[id] = f2bf(W1[k * NHID + n]);
  } else {                             // W2t[n][k] = W2[k][n], 256x128 -> 128x256
    int id = (b - 5512) * 256 + t;     // 0..32767
    int n = id >> 8, k = id & 255;
    w2t[id] = f2bf(W2[k * NHID2 + n]);
  }
}

// ---- bf16 MFMA GEMM: C[M][N] = A[M][K] @ Bt[N][K]^T, optional bf16 output ----
// 4 waves in 2x2; no LDS (operands small + L2/L3-resident, fragments are contiguous short8)
template<int WR, int WC, bool OUT_BF16>
__launch_bounds__(256)
__global__ void k_gemm_bf16(const ushort* __restrict__ A, const ushort* __restrict__ Bt,
                            void* __restrict__ Cv, int M, int N, int K){
  const int lane = threadIdx.x & 63;
  const int w    = threadIdx.x >> 6;
  const int wr   = w >> 1, wc = w & 1;
  const int r16  = lane & 15;
  const int kg   = lane >> 4;           // 0..3
  const int BM = 2 * WR * 16, BN = 2 * WC * 16;
  const int row0 = blockIdx.x * BM + wr * WR * 16;
  const int col0 = blockIdx.y * BN + wc * WC * 16;

  f32x4 acc[WR][WC];
  #pragma unroll
  for (int r = 0; r < WR; r++)
    #pragma unroll
    for (int c = 0; c < WC; c++)
      acc[r][c] = (f32x4){0.f, 0.f, 0.f, 0.f};

  for (int k0 = 0; k0 < K; k0 += 32){
    bf16x8 a[WR], b[WC];
    #pragma unroll
    for (int r = 0; r < WR; r++){
      int ar = row0 + r * 16 + r16;
      if (ar >= M) ar = M - 1;                       // clamp: safe read, store masked later
      a[r] = *(const bf16x8*)(A + (size_t)ar * K + k0 + kg * 8);
    }
    #pragma unroll
    for (int c = 0; c < WC; c++){
      int bc = col0 + c * 16 + r16;                  // grid sized so always < N
      b[c] = *(const bf16x8*)(Bt + (size_t)bc * K + k0 + kg * 8);
    }
    #pragma unroll
    for (int r = 0; r < WR; r++)
      #pragma unroll
      for (int c = 0; c < WC; c++)
        acc[r][c] = __builtin_amdgcn_mfma_f32_16x16x32_bf16(a[r], b[c], acc[r][c], 0, 0, 0);
  }

  // C/D layout (m89-verified): row = kg*4 + i, col = lane&15 within each 16x16 frag
  #pragma unroll
  for (int r = 0; r < WR; r++)
    #pragma unroll
    for (int c = 0; c < WC; c++){
      int col = col0 + c * 16 + r16;
      #pragma unroll
      for (int i = 0; i < 4; i++){
        int row = row0 + r * 16 + kg * 4 + i;
        if (row < M){
          if (OUT_BF16) ((ushort*)Cv)[(size_t)row * N + col] = f2bf(acc[r][c][i]);
          else          ((float*) Cv)[(size_t)row * N + col] = acc[r][c][i];
        }
      }
    }
}

// ---- SpMM layer 1: SINGLE-pass adj row scan (register-cached), deterministic
//      compaction, H[i,:] = relu(sum_j a_ij * XW1[j,:] + b1) bf16; persist list ----
__launch_bounds__(256)
__global__ void k_spmm1(const float* __restrict__ adj, const ushort* __restrict__ xw1b,
                        const float* __restrict__ b1, ushort* __restrict__ Hb,
                        int* __restrict__ row_nnz, int* __restrict__ pj, float* __restrict__ pa){
  const int r = blockIdx.x;
  const int t = threadIdx.x;
  const float* row = adj + (size_t)r * N_NODES;

  __shared__ int   sc[256];
  __shared__ int   lj[CAP];
  __shared__ float la[CAP];

  // single coalesced pass: iter v covers block elements [v*1024, v*1024+1024)
  // (each wave reads 1KB contiguous per instruction); 9 full iters + 784-elem tail
  float4 vals[10];
  #pragma unroll
  for (int v = 0; v < 9; v++)
    vals[v] = *(const float4*)(row + v * 1024 + t * 4);
  vals[9] = (float4){0.f, 0.f, 0.f, 0.f};
  if (t < 196) vals[9] = *(const float4*)(row + 9216 + t * 4);

  int cnt = 0;
  #pragma unroll
  for (int v = 0; v < 10; v++)
    cnt += (vals[v].x != 0.f) + (vals[v].y != 0.f) + (vals[v].z != 0.f) + (vals[v].w != 0.f);

  // inclusive Hillis-Steele prefix over 256 threads -> deterministic compaction order
  sc[t] = cnt; __syncthreads();
  for (int off = 1; off < 256; off <<= 1){
    int u = 0;
    if (t >= off) u = sc[t - off];
    __syncthreads();
    sc[t] += u;
    __syncthreads();
  }
  int pos   = sc[t] - cnt;      // exclusive prefix
  int total = sc[255];

  // compact from registers (no second global read) + persist to workspace
  #pragma unroll
  for (int v = 0; v < 10; v++){
    float q[4] = {vals[v].x, vals[v].y, vals[v].z, vals[v].w};
    #pragma unroll
    for (int e = 0; e < 4; e++){
      if (q[e] != 0.f && pos < CAP){
        int idx = v * 1024 + t * 4 + e;
        lj[pos] = idx; la[pos] = q[e];
        pj[(size_t)r * CAP + pos] = idx;
        pa[(size_t)r * CAP + pos] = q[e];
        pos++;
      }
    }
  }
  __syncthreads();

  int n = min(total, CAP);
  if (t == 0) row_nnz[r] = n;

  // thread t owns output column t; gather bf16 rows of XW1 (512B/wave coalesced)
  float acc = 0.f;
  for (int k = 0; k < n; k++)
    acc += la[k] * bf2f(xw1b[(size_t)lj[k] * NHID + t]);
  Hb[(size_t)r * NHID + t] = f2bf(fmaxf(acc + b1[t], 0.f));
}

// ---- SpMM layer 2: replay stored sparse list, out = relu(sum a*HW2 + b2) ----
__launch_bounds__(128)
__global__ void k_spmm2(const int* __restrict__ row_nnz, const int* __restrict__ pj,
                        const float* __restrict__ pa, const float* __restrict__ hw2,
                        const float* __restrict__ b2, float* __restrict__ out){
  const int r = blockIdx.x;
  const int t = threadIdx.x;
  __shared__ int   lj[CAP];
  __shared__ float la[CAP];
  const int n = row_nnz[r];
  for (int k = t; k < n; k += 128){
    lj[k] = pj[(size_t)r * CAP + k];
    la[k] = pa[(size_t)r * CAP + k];
  }
  __syncthreads();
  float acc = 0.f;
  for (int k = 0; k < n; k++)
    acc += la[k] * hw2[(size_t)lj[k] * NHID2 + t];
  out[(size_t)r * NHID2 + t] = fmaxf(acc + b2[t], 0.f);
}

extern "C" void kernel_launch(void* const* d_in, const int* in_sizes, int n_in,
                              void* d_out, int out_size, void* d_ws, size_t ws_size,
                              hipStream_t stream){
  const float* x   = (const float*)d_in[0];
  const float* adj = (const float*)d_in[1];
  const float* W1  = (const float*)d_in[2];
  const float* b1  = (const float*)d_in[3];
  const float* W2  = (const float*)d_in[4];
  const float* b2  = (const float*)d_in[5];
  float* out = (float*)d_out;
  char*  ws  = (char*)d_ws;

  // workspace layout (16B-aligned), total ~36.2 MB
  ushort* xb   = (ushort*)(ws);              // x bf16:    10000*512*2 = 10,240,000
  ushort* w1t  = (ushort*)(ws + 10240000);   // W1t bf16:  256*512*2   =    262,144
  ushort* w2t  = (ushort*)(ws + 10502144);   // W2t bf16:  128*256*2   =     65,536
  ushort* xw1b = (ushort*)(ws + 10567680);   // XW1 bf16:  10000*256*2 =  5,120,000
  ushort* Hb   = (ushort*)(ws + 15687680);   // H bf16:    10000*256*2 =  5,120,000
  float*  hw2  = (float*)(ws + 20807680);    // HW2 f32:   10000*128*4 =  5,120,000
  int*    nnz  = (int*)(ws + 25927680);      // 10000*4
  int*    pj   = (int*)(ws + 25967680);      // 10000*128*4 = 5,120,000
  float*  pa   = (float*)(ws + 31087680);    // 10000*128*4 = 5,120,000

  k_cvt_all<<<5640, 256, 0, stream>>>(x, W1, W2, xb, w1t, w2t);

  // GEMM1: XW1b = x @ W1  (M=10000, K=512, N=256), 64x64 tiles -> 628 blocks
  k_gemm_bf16<2,2,true><<<dim3(157, 4), 256, 0, stream>>>(xb, w1t, xw1b, N_NODES, NHID, NFEAT);

  // layer-1 sparse aggregate + bias + relu (single adj pass, persists sparse list)
  k_spmm1<<<N_NODES, 256, 0, stream>>>(adj, xw1b, b1, Hb, nnz, pj, pa);

  // GEMM2: HW2 = H @ W2  (M=10000, K=256, N=128), 64x64 tiles -> 314 blocks
  k_gemm_bf16<2,2,false><<<dim3(157, 2), 256, 0, stream>>>(Hb, w2t, hw2, N_NODES, NHID2, NHID);

  // layer-2 sparse aggregate + bias + relu
  k_spmm2<<<N_NODES, 128, 0, stream>>>(nnz, pj, pa, hw2, b2, out);
}

// Round 3
// 157.060 us; speedup vs baseline: 1.3115x; 1.0298x over previous
//
#include <hip/hip_runtime.h>

#define N_NODES 10000
#define NFEAT   512
#define NHID    256
#define NHID2   128
#define CAP     128   // max nnz/row stored; binomial(10000,0.005) mean 50, sd 7 -> 128 is >11 sigma

typedef __attribute__((ext_vector_type(8))) short bf16x8;
typedef __attribute__((ext_vector_type(4))) float f32x4;

__device__ __forceinline__ ushort f2bf(float f){
  union { float f; unsigned u; } v; v.f = f;
  unsigned r = v.u + 0x7FFFu + ((v.u >> 16) & 1u);   // round-to-nearest-even
  return (ushort)(r >> 16);
}
__device__ __forceinline__ float bf2f(ushort u){
  union { unsigned u; float f; } v; v.u = ((unsigned)u) << 16; return v.f;
}

// ---- fused converts: x -> bf16, W1 -> W1t bf16, W2 -> W2t bf16 (one launch) ----
__global__ void k_cvt_all(const float* __restrict__ x, const float* __restrict__ W1,
                          const float* __restrict__ W2, ushort* __restrict__ xb,
                          ushort* __restrict__ w1t, ushort* __restrict__ w2t){
  const int b = blockIdx.x, t = threadIdx.x;
  if (b < 5000){                       // x: 5.12M elems, 4/thread, exact grid
    int i = (b * 256 + t) * 4;
    float4 q = *(const float4*)(x + i);
    ushort4 o; o.x = f2bf(q.x); o.y = f2bf(q.y); o.z = f2bf(q.z); o.w = f2bf(q.w);
    *(ushort4*)(xb + i) = o;
  } else if (b < 5512){                // W1t[n][k] = W1[k][n], 512x256 -> 256x512
    int id = (b - 5000) * 256 + t;
    int n = id >> 9, k = id & 511;
    w1t[id] = f2bf(W1[k * NHID + n]);
  } else {                             // W2t[n][k] = W2[k][n], 256x128 -> 128x256
    int id = (b - 5512) * 256 + t;
    int n = id >> 8, k = id & 255;
    w2t[id] = f2bf(W2[k * NHID2 + n]);
  }
}

// ---- bf16 MFMA GEMM: C[M][N] = A[M][K] @ Bt[N][K]^T, optional bf16 output ----
// 4 waves in 2x2; no LDS (operands small + L2/L3-resident, fragments contiguous short8)
template<int WR, int WC, bool OUT_BF16>
__launch_bounds__(256)
__global__ void k_gemm_bf16(const ushort* __restrict__ A, const ushort* __restrict__ Bt,
                            void* __restrict__ Cv, int M, int N, int K){
  const int lane = threadIdx.x & 63;
  const int w    = threadIdx.x >> 6;
  const int wr   = w >> 1, wc = w & 1;
  const int r16  = lane & 15;
  const int kg   = lane >> 4;           // 0..3
  const int BM = 2 * WR * 16, BN = 2 * WC * 16;
  const int row0 = blockIdx.x * BM + wr * WR * 16;
  const int col0 = blockIdx.y * BN + wc * WC * 16;

  f32x4 acc[WR][WC];
  #pragma unroll
  for (int r = 0; r < WR; r++)
    #pragma unroll
    for (int c = 0; c < WC; c++)
      acc[r][c] = (f32x4){0.f, 0.f, 0.f, 0.f};

  for (int k0 = 0; k0 < K; k0 += 32){
    bf16x8 a[WR], b[WC];
    #pragma unroll
    for (int r = 0; r < WR; r++){
      int ar = row0 + r * 16 + r16;
      if (ar >= M) ar = M - 1;                       // clamp: safe read, store masked later
      a[r] = *(const bf16x8*)(A + (size_t)ar * K + k0 + kg * 8);
    }
    #pragma unroll
    for (int c = 0; c < WC; c++){
      int bc = col0 + c * 16 + r16;                  // grid sized so always < N
      b[c] = *(const bf16x8*)(Bt + (size_t)bc * K + k0 + kg * 8);
    }
    #pragma unroll
    for (int r = 0; r < WR; r++)
      #pragma unroll
      for (int c = 0; c < WC; c++)
        acc[r][c] = __builtin_amdgcn_mfma_f32_16x16x32_bf16(a[r], b[c], acc[r][c], 0, 0, 0);
  }

  // C/D layout (m89-verified): row = kg*4 + i, col = lane&15 within each 16x16 frag
  #pragma unroll
  for (int r = 0; r < WR; r++)
    #pragma unroll
    for (int c = 0; c < WC; c++){
      int col = col0 + c * 16 + r16;
      #pragma unroll
      for (int i = 0; i < 4; i++){
        int row = row0 + r * 16 + kg * 4 + i;
        if (row < M){
          if (OUT_BF16) ((ushort*)Cv)[(size_t)row * N + col] = f2bf(acc[r][c][i]);
          else          ((float*) Cv)[(size_t)row * N + col] = acc[r][c][i];
        }
      }
    }
}

// ---- SpMM layer 1: single-pass adj scan (register-cached), shfl-scan compaction,
//      8-way k-parallel gather, H = relu(A@XW1 + b1) bf16; persist packed list ----
__launch_bounds__(256)
__global__ void k_spmm1(const float* __restrict__ adj, const ushort* __restrict__ xw1b,
                        const float* __restrict__ b1, ushort* __restrict__ Hb,
                        int* __restrict__ row_nnz, int2* __restrict__ pja){
  const int r = blockIdx.x;
  const int t = threadIdx.x;
  const int lane = t & 63, w = t >> 6;
  const float* row = adj + (size_t)r * N_NODES;

  __shared__ int   swave[4];
  __shared__ int   lj[CAP];
  __shared__ float la[CAP];
  __shared__ float part[8 * NHID];   // 8 KB partials

  // single coalesced scan: 9 full float4 iters + 784-elem tail
  float4 vals[10];
  #pragma unroll
  for (int v = 0; v < 9; v++)
    vals[v] = *(const float4*)(row + v * 1024 + t * 4);
  vals[9] = (float4){0.f, 0.f, 0.f, 0.f};
  if (t < 196) vals[9] = *(const float4*)(row + 9216 + t * 4);

  int cnt = 0;
  #pragma unroll
  for (int v = 0; v < 10; v++)
    cnt += (vals[v].x != 0.f) + (vals[v].y != 0.f) + (vals[v].z != 0.f) + (vals[v].w != 0.f);

  // wave-level inclusive scan (no barriers) + one cross-wave LDS step
  int incl = cnt;
  #pragma unroll
  for (int d = 1; d < 64; d <<= 1){
    int u = __shfl_up(incl, d, 64);
    if (lane >= d) incl += u;
  }
  if (lane == 63) swave[w] = incl;
  __syncthreads();
  int woff = 0, total = 0;
  #pragma unroll
  for (int i = 0; i < 4; i++){
    int s = swave[i];
    total += s;
    if (i < w) woff += s;
  }
  int pos = woff + incl - cnt;       // exclusive prefix -> deterministic compaction

  #pragma unroll
  for (int v = 0; v < 10; v++){
    float q[4] = {vals[v].x, vals[v].y, vals[v].z, vals[v].w};
    #pragma unroll
    for (int e = 0; e < 4; e++){
      if (q[e] != 0.f && pos < CAP){
        int idx = v * 1024 + t * 4 + e;
        lj[pos] = idx; la[pos] = q[e];
        pja[(size_t)r * CAP + pos] = make_int2(idx, __float_as_int(q[e]));
        pos++;
      }
    }
  }
  __syncthreads();
  const int n = min(total, CAP);
  if (t == 0) row_nnz[r] = n;

  // 8-way k-parallel gather: slot = wave*2 + half-wave; half-wave covers 256 cols
  // via bf16x8 (16B/lane). 8 independent k's in flight -> L2/L3 latency hidden.
  const int slot = w * 2 + (lane >> 5);
  const int l32  = lane & 31;
  float accv[8] = {0.f,0.f,0.f,0.f,0.f,0.f,0.f,0.f};
  for (int k = slot; k < n; k += 8){
    bf16x8 rv = *(const bf16x8*)(xw1b + (size_t)lj[k] * NHID + l32 * 8);
    float a = la[k];
    #pragma unroll
    for (int j = 0; j < 8; j++)
      accv[j] += a * bf2f((ushort)rv[j]);
  }
  #pragma unroll
  for (int j = 0; j < 8; j++)
    part[slot * NHID + l32 * 8 + j] = accv[j];
  __syncthreads();

  float s = 0.f;
  #pragma unroll
  for (int i = 0; i < 8; i++)
    s += part[i * NHID + t];
  Hb[(size_t)r * NHID + t] = f2bf(fmaxf(s + b1[t], 0.f));
}

// ---- SpMM layer 2: replay packed list, 8-way k-parallel float4 gather ----
__launch_bounds__(256)
__global__ void k_spmm2(const int* __restrict__ row_nnz, const int2* __restrict__ pja,
                        const float* __restrict__ hw2, const float* __restrict__ b2,
                        float* __restrict__ out){
  const int r = blockIdx.x;
  const int t = threadIdx.x;
  __shared__ int   lj[CAP];
  __shared__ float la[CAP];
  __shared__ float part[8 * NHID2];  // 4 KB
  const int n = row_nnz[r];
  if (t < n){
    int2 p = pja[(size_t)r * CAP + t];
    lj[t] = p.x; la[t] = __int_as_float(p.y);
  }
  __syncthreads();

  const int lane = t & 63, w = t >> 6;
  const int slot = w * 2 + (lane >> 5);  // 0..7
  const int l32  = lane & 31;            // lanes 0..31 cover 128 cols via float4
  float4 accv = (float4){0.f,0.f,0.f,0.f};
  for (int k = slot; k < n; k += 8){
    float4 rv = *(const float4*)(hw2 + (size_t)lj[k] * NHID2 + l32 * 4);
    float a = la[k];
    accv.x += a * rv.x; accv.y += a * rv.y; accv.z += a * rv.z; accv.w += a * rv.w;
  }
  *(float4*)(part + slot * NHID2 + l32 * 4) = accv;
  __syncthreads();

  if (t < NHID2){
    float s = 0.f;
    #pragma unroll
    for (int i = 0; i < 8; i++)
      s += part[i * NHID2 + t];
    out[(size_t)r * NHID2 + t] = fmaxf(s + b2[t], 0.f);
  }
}

extern "C" void kernel_launch(void* const* d_in, const int* in_sizes, int n_in,
                              void* d_out, int out_size, void* d_ws, size_t ws_size,
                              hipStream_t stream){
  const float* x   = (const float*)d_in[0];
  const float* adj = (const float*)d_in[1];
  const float* W1  = (const float*)d_in[2];
  const float* b1  = (const float*)d_in[3];
  const float* W2  = (const float*)d_in[4];
  const float* b2  = (const float*)d_in[5];
  float* out = (float*)d_out;
  char*  ws  = (char*)d_ws;

  // workspace layout (16B-aligned), total ~36.2 MB
  ushort* xb   = (ushort*)(ws);              // x bf16:    10,240,000
  ushort* w1t  = (ushort*)(ws + 10240000);   // W1t bf16:     262,144
  ushort* w2t  = (ushort*)(ws + 10502144);   // W2t bf16:      65,536
  ushort* xw1b = (ushort*)(ws + 10567680);   // XW1 bf16:   5,120,000
  ushort* Hb   = (ushort*)(ws + 15687680);   // H bf16:     5,120,000
  float*  hw2  = (float*)(ws + 20807680);    // HW2 f32:    5,120,000
  int*    nnz  = (int*)(ws + 25927680);      // 40,000
  int2*   pja  = (int2*)(ws + 25967680);     // packed (j,a): 10,240,000

  k_cvt_all<<<5640, 256, 0, stream>>>(x, W1, W2, xb, w1t, w2t);

  // GEMM1: XW1b = x @ W1  (M=10000,K=512,N=256), 128x64 tiles -> 316 blocks, 8 MFMA/k-step
  k_gemm_bf16<4,2,true><<<dim3(79, 4), 256, 0, stream>>>(xb, w1t, xw1b, N_NODES, NHID, NFEAT);

  // layer-1 sparse aggregate + bias + relu (single adj pass, persists packed list)
  k_spmm1<<<N_NODES, 256, 0, stream>>>(adj, xw1b, b1, Hb, nnz, pja);

  // GEMM2: HW2 = H @ W2  (M=10000,K=256,N=128), 64x64 tiles -> 314 blocks
  k_gemm_bf16<2,2,false><<<dim3(157, 2), 256, 0, stream>>>(Hb, w2t, hw2, N_NODES, NHID2, NHID);

  // layer-2 sparse aggregate + bias + relu
  k_spmm2<<<N_NODES, 256, 0, stream>>>(nnz, pja, hw2, b2, out);
}

// Round 4
// 156.798 us; speedup vs baseline: 1.3137x; 1.0017x over previous
//
#include <hip/hip_runtime.h>

#define N_NODES 10000
#define NFEAT   512
#define NHID    256
#define NHID2   128
#define CAP     128   // max nnz/row stored; binomial(10000,0.005) mean 50, sd 7 -> 128 is >11 sigma

typedef __attribute__((ext_vector_type(8))) short bf16x8;
typedef __attribute__((ext_vector_type(4))) float f32x4;

__device__ __forceinline__ ushort f2bf(float f){
  union { float f; unsigned u; } v; v.f = f;
  unsigned r = v.u + 0x7FFFu + ((v.u >> 16) & 1u);   // round-to-nearest-even
  return (ushort)(r >> 16);
}
__device__ __forceinline__ float bf2f(ushort u){
  union { unsigned u; float f; } v; v.u = ((unsigned)u) << 16; return v.f;
}

// ---- K1: fused adj scan/extract (blocks 0..9999) + bf16 converts (rest) ----
// The HBM-bound 400MB adj scan hides all convert work. Scan path carries no
// gather state: 16B LDS, registers only for the row cache.
__launch_bounds__(256)
__global__ void k_scan_cvt(const float* __restrict__ adj, const float* __restrict__ x,
                           const float* __restrict__ W1, const float* __restrict__ W2,
                           ushort* __restrict__ xb, ushort* __restrict__ w1t,
                           ushort* __restrict__ w2t, int* __restrict__ row_nnz,
                           int2* __restrict__ pja){
  const int b = blockIdx.x, t = threadIdx.x;

  if (b >= N_NODES){                    // ---- convert path ----
    if (b < 15000){                     // x: 4 elems/thread, exact grid
      int i = ((b - N_NODES) * 256 + t) * 4;
      float4 q = *(const float4*)(x + i);
      ushort4 o; o.x = f2bf(q.x); o.y = f2bf(q.y); o.z = f2bf(q.z); o.w = f2bf(q.w);
      *(ushort4*)(xb + i) = o;
    } else if (b < 15512){              // W1t[n][k] = W1[k][n]
      int id = (b - 15000) * 256 + t;
      int n = id >> 9, k = id & 511;
      w1t[id] = f2bf(W1[k * NHID + n]);
    } else {                            // W2t[n][k] = W2[k][n]
      int id = (b - 15512) * 256 + t;
      int n = id >> 8, k = id & 255;
      w2t[id] = f2bf(W2[k * NHID2 + n]);
    }
    return;
  }

  // ---- scan path: row b, single coalesced pass, register-cached ----
  const int r = b;
  const int lane = t & 63, w = t >> 6;
  const float* row = adj + (size_t)r * N_NODES;
  __shared__ int swave[4];

  float4 vals[10];
  #pragma unroll
  for (int v = 0; v < 9; v++)
    vals[v] = *(const float4*)(row + v * 1024 + t * 4);
  vals[9] = (float4){0.f, 0.f, 0.f, 0.f};
  if (t < 196) vals[9] = *(const float4*)(row + 9216 + t * 4);

  int cnt = 0;
  #pragma unroll
  for (int v = 0; v < 10; v++)
    cnt += (vals[v].x != 0.f) + (vals[v].y != 0.f) + (vals[v].z != 0.f) + (vals[v].w != 0.f);

  // wave shfl-scan + one cross-wave LDS step -> deterministic compaction order
  int incl = cnt;
  #pragma unroll
  for (int d = 1; d < 64; d <<= 1){
    int u = __shfl_up(incl, d, 64);
    if (lane >= d) incl += u;
  }
  if (lane == 63) swave[w] = incl;
  __syncthreads();
  int woff = 0, total = 0;
  #pragma unroll
  for (int i = 0; i < 4; i++){
    int s = swave[i];
    total += s;
    if (i < w) woff += s;
  }
  int pos = woff + incl - cnt;          // exclusive prefix

  #pragma unroll
  for (int v = 0; v < 10; v++){
    float q[4] = {vals[v].x, vals[v].y, vals[v].z, vals[v].w};
    #pragma unroll
    for (int e = 0; e < 4; e++){
      if (q[e] != 0.f && pos < CAP){
        pja[(size_t)r * CAP + pos] = make_int2(v * 1024 + t * 4 + e, __float_as_int(q[e]));
        pos++;
      }
    }
  }
  if (t == 0) row_nnz[r] = min(total, CAP);
}

// ---- bf16 MFMA GEMM, 2x-unrolled double-buffered fragment pipeline ----
// C[M][N] = A[M][K] @ Bt[N][K]^T; no LDS (operands L2/L3-resident, frags contiguous)
template<int WR, int WC, bool OUT_BF16, int K>
__launch_bounds__(256)
__global__ void k_gemm(const ushort* __restrict__ A, const ushort* __restrict__ Bt,
                       void* __restrict__ Cv, int M, int N){
  const int lane = threadIdx.x & 63;
  const int w    = threadIdx.x >> 6;
  const int wr   = w >> 1, wc = w & 1;
  const int r16  = lane & 15;
  const int kg   = lane >> 4;           // 0..3
  const int BM = 2 * WR * 16, BN = 2 * WC * 16;
  const int row0 = blockIdx.x * BM + wr * WR * 16;
  const int col0 = blockIdx.y * BN + wc * WC * 16;

  int arow[WR], bcol[WC];
  #pragma unroll
  for (int r = 0; r < WR; r++){
    int ar = row0 + r * 16 + r16;
    arow[r] = (ar >= M) ? (M - 1) : ar;          // clamp: safe read, store masked later
  }
  #pragma unroll
  for (int c = 0; c < WC; c++) bcol[c] = col0 + c * 16 + r16;

  f32x4 acc[WR][WC];
  #pragma unroll
  for (int r = 0; r < WR; r++)
    #pragma unroll
    for (int c = 0; c < WC; c++)
      acc[r][c] = (f32x4){0.f, 0.f, 0.f, 0.f};

  bf16x8 aA[WR], bA[WC], aB[WR], bB[WC];
  auto LOADF = [&](bf16x8* a, bf16x8* b, int k0){
    #pragma unroll
    for (int r = 0; r < WR; r++)
      a[r] = *(const bf16x8*)(A + (size_t)arow[r] * K + k0 + kg * 8);
    #pragma unroll
    for (int c = 0; c < WC; c++)
      b[c] = *(const bf16x8*)(Bt + (size_t)bcol[c] * K + k0 + kg * 8);
  };
  auto MM = [&](bf16x8* a, bf16x8* b){
    #pragma unroll
    for (int r = 0; r < WR; r++)
      #pragma unroll
      for (int c = 0; c < WC; c++)
        acc[r][c] = __builtin_amdgcn_mfma_f32_16x16x32_bf16(a[r], b[c], acc[r][c], 0, 0, 0);
  };

  LOADF(aA, bA, 0);
  #pragma unroll
  for (int k0 = 0; k0 < K; k0 += 64){
    if (k0 + 32 < K) LOADF(aB, bB, k0 + 32);     // prefetch overlaps MFMA below
    MM(aA, bA);
    if (k0 + 64 < K) LOADF(aA, bA, k0 + 64);
    if (k0 + 32 < K) MM(aB, bB);
  }

  // C/D layout (m89-verified): row = kg*4 + i, col = lane&15 within each 16x16 frag
  #pragma unroll
  for (int r = 0; r < WR; r++)
    #pragma unroll
    for (int c = 0; c < WC; c++){
      int col = col0 + c * 16 + r16;
      #pragma unroll
      for (int i = 0; i < 4; i++){
        int row = row0 + r * 16 + kg * 4 + i;
        if (row < M){
          if (OUT_BF16) ((ushort*)Cv)[(size_t)row * N + col] = f2bf(acc[r][c][i]);
          else          ((float*) Cv)[(size_t)row * N + col] = acc[r][c][i];
        }
      }
    }
}

// ---- agg1: H[r,:] = relu(sum_k a_k * XW1[j_k,:] + b1), 8-slot k-parallel bf16 gather ----
__launch_bounds__(256)
__global__ void k_agg1(const int* __restrict__ row_nnz, const int2* __restrict__ pja,
                       const ushort* __restrict__ xw1b, const float* __restrict__ b1,
                       ushort* __restrict__ Hb){
  const int r = blockIdx.x, t = threadIdx.x;
  __shared__ int   lj[CAP];
  __shared__ float la[CAP];
  __shared__ float part[8 * NHID];   // 8 KB
  const int n = row_nnz[r];
  if (t < n){
    int2 p = pja[(size_t)r * CAP + t];
    lj[t] = p.x; la[t] = __int_as_float(p.y);
  }
  __syncthreads();

  const int slot = t >> 5, l32 = t & 31;   // 8 slots x 32 lanes; lane covers 8 cols
  float accv[8] = {0.f,0.f,0.f,0.f,0.f,0.f,0.f,0.f};
  for (int k = slot; k < n; k += 8){
    bf16x8 rv = *(const bf16x8*)(xw1b + (size_t)lj[k] * NHID + l32 * 8);
    float a = la[k];
    #pragma unroll
    for (int j = 0; j < 8; j++)
      accv[j] += a * bf2f((ushort)rv[j]);
  }
  #pragma unroll
  for (int j = 0; j < 8; j++)
    part[slot * NHID + l32 * 8 + j] = accv[j];
  __syncthreads();

  float s = 0.f;
  #pragma unroll
  for (int i = 0; i < 8; i++)
    s += part[i * NHID + t];
  Hb[(size_t)r * NHID + t] = f2bf(fmaxf(s + b1[t], 0.f));
}

// ---- agg2: out[r,:] = relu(sum_k a_k * HW2[j_k,:] + b2), 16-slot bf16 gather ----
__launch_bounds__(256)
__global__ void k_agg2(const int* __restrict__ row_nnz, const int2* __restrict__ pja,
                       const ushort* __restrict__ hw2b, const float* __restrict__ b2,
                       float* __restrict__ out){
  const int r = blockIdx.x, t = threadIdx.x;
  __shared__ int   lj[CAP];
  __shared__ float la[CAP];
  __shared__ float part[16 * NHID2];  // 8 KB
  const int n = row_nnz[r];
  if (t < n){
    int2 p = pja[(size_t)r * CAP + t];
    lj[t] = p.x; la[t] = __int_as_float(p.y);
  }
  __syncthreads();

  const int slot = t >> 4, l16 = t & 15;   // 16 slots x 16 lanes; lane covers 8 cols
  float accv[8] = {0.f,0.f,0.f,0.f,0.f,0.f,0.f,0.f};
  for (int k = slot; k < n; k += 16){
    bf16x8 rv = *(const bf16x8*)(hw2b + (size_t)lj[k] * NHID2 + l16 * 8);
    float a = la[k];
    #pragma unroll
    for (int j = 0; j < 8; j++)
      accv[j] += a * bf2f((ushort)rv[j]);
  }
  #pragma unroll
  for (int j = 0; j < 8; j++)
    part[slot * NHID2 + l16 * 8 + j] = accv[j];
  __syncthreads();

  if (t < NHID2){
    float s = 0.f;
    #pragma unroll
    for (int i = 0; i < 16; i++)
      s += part[i * NHID2 + t];
    out[(size_t)r * NHID2 + t] = fmaxf(s + b2[t], 0.f);
  }
}

extern "C" void kernel_launch(void* const* d_in, const int* in_sizes, int n_in,
                              void* d_out, int out_size, void* d_ws, size_t ws_size,
                              hipStream_t stream){
  const float* x   = (const float*)d_in[0];
  const float* adj = (const float*)d_in[1];
  const float* W1  = (const float*)d_in[2];
  const float* b1  = (const float*)d_in[3];
  const float* W2  = (const float*)d_in[4];
  const float* b2  = (const float*)d_in[5];
  float* out = (float*)d_out;
  char*  ws  = (char*)d_ws;

  // workspace layout (8/16B-aligned), total ~33.6 MB
  ushort* xb   = (ushort*)(ws);              // x bf16:     10,240,000
  ushort* w1t  = (ushort*)(ws + 10240000);   // W1t bf16:      262,144
  ushort* w2t  = (ushort*)(ws + 10502144);   // W2t bf16:       65,536
  ushort* xw1b = (ushort*)(ws + 10567680);   // XW1 bf16:    5,120,000
  ushort* Hb   = (ushort*)(ws + 15687680);   // H bf16:      5,120,000
  ushort* hw2b = (ushort*)(ws + 20807680);   // HW2 bf16:    2,560,000
  int*    nnz  = (int*)(ws + 23367680);      // 40,000
  int2*   pja  = (int2*)(ws + 23407680);     // packed (j,a): 10,240,000

  // K1: adj scan/extract (10000 blocks) overlapped with all bf16 converts (5640 blocks)
  k_scan_cvt<<<15640, 256, 0, stream>>>(adj, x, W1, W2, xb, w1t, w2t, nnz, pja);

  // K2: XW1b = x @ W1  (M=10000,K=512,N=256), 128x64 tiles -> 316 blocks
  k_gemm<4,2,true,NFEAT><<<dim3(79, 4), 256, 0, stream>>>(xb, w1t, xw1b, N_NODES, NHID);

  // K3: layer-1 aggregate + bias + relu
  k_agg1<<<N_NODES, 256, 0, stream>>>(nnz, pja, xw1b, b1, Hb);

  // K4: HW2b = H @ W2  (M=10000,K=256,N=128), 64x64 tiles -> 314 blocks
  k_gemm<2,2,true,NHID><<<dim3(157, 2), 256, 0, stream>>>(Hb, w2t, hw2b, N_NODES, NHID2);

  // K5: layer-2 aggregate + bias + relu
  k_agg2<<<N_NODES, 256, 0, stream>>>(nnz, pja, hw2b, b2, out);
}